// Round 12
// baseline (107.902 us; speedup 1.0000x reference)
//
#include <hip/hip_runtime.h>
#include <math.h>

// PolicyGradient_28819230556839: 3-layer post-norm transformer encoder,
// B=8192, S=9, D=3, H=3 (head dim 1), DFF=2048, then logits->softmax->prod->softmax.
// R12: SCALAR v_fma FFN at the R11 structure — the first clean scalar-vs-packed
// A/B. Ledger: R4/R11 busy (184-188K cyc/SIMD) fits v_pk_fma_f32 at QUARTER
// rate (8cyc); two scalar fma = 4cyc beat one pk = 8cyc. R10's scalar test was
// void (natural VGPR=64 -> serialized chains, 4cyc effective). Tied inline asm
// + t[9] battery + acc[27] forces the parallel-chain codegen.

constexpr int S   = 9;
constexpr int D   = 3;
constexpr int DFF = 2048;
constexpr int L   = 3;
constexpr int G   = 16;          // threads cooperating on one batch element
constexpr int BLK = 512;
constexpr int BPB = BLK / G;     // batch elements per block = 32
constexpr int FPT = DFF / G;     // f-values per thread = 128
constexpr int NROW = 27;         // attention rows = H*S
constexpr int ATT_STRIDE = 33;
constexpr float EPS = 1e-5f;

typedef float v2f __attribute__((ext_vector_type(2)));
typedef float v4f __attribute__((ext_vector_type(4)));

// scalar fma, fresh dest (no mov: dest is chain-local)
#define FMA_INIT(d, a, bb, c) \
    asm("v_fma_f32 %0, %1, %2, %3" : "=v"(d) : "v"(a), "v"(bb), "v"(c))
// scalar fma, tied dest: d = a*b + d (in-place accumulate)
#define FMA_ACC(d, a, bb) \
    asm("v_fma_f32 %0, %1, %2, %0" : "+v"(d) : "v"(a), "v"(bb))

__launch_bounds__(BLK)
__global__ void tf_policy_kernel(const float* __restrict__ x,
                                 const float* __restrict__ Wqkv,
                                 const float* __restrict__ bqkv,
                                 const float* __restrict__ Wo,
                                 const float* __restrict__ bo,
                                 const float* __restrict__ g1,
                                 const float* __restrict__ be1,
                                 const float* __restrict__ W1,
                                 const float* __restrict__ bf1,
                                 const float* __restrict__ W2,
                                 const float* __restrict__ bf2,
                                 const float* __restrict__ g2,
                                 const float* __restrict__ be2,
                                 const float* __restrict__ Wfin,
                                 float* __restrict__ out)
{
    // s_w1[f]  = {W1[f][0], W1[f][1], W1[f][2], bf1[f]}   32 KB (b128/f)
    // s_w2a[f] = {W2[0][f], W2[1][f]}                     16 KB (b64/f)
    // s_w2z[f] =  W2[2][f]                                 8 KB (b32/f)
    __shared__ v4f   s_w1[DFF];
    __shared__ v2f   s_w2a[DFF];
    __shared__ float s_w2z[DFF];
    __shared__ float s_att[BPB * ATT_STRIDE];   // ~4.2 KB

    const int tid = threadIdx.x;
    const int grp = tid >> 4;      // which batch element within block
    const int sub = tid & 15;      // lane within the 16-thread group
    const int b   = blockIdx.x * BPB + grp;

    // per-thread hidden state h[9][3]
    float h[S][D];
    {
        const float* xr = x + (size_t)b * (S * D);
        #pragma unroll
        for (int s = 0; s < S; ++s)
            #pragma unroll
            for (int d = 0; d < D; ++d)
                h[s][d] = xr[s * D + d];
    }

    for (int l = 0; l < L; ++l) {
        __syncthreads();   // protect LDS from previous layer's readers
        // ---- stage W1+b1 (v4f) and W2 (v2f + f32) into LDS ----
        {
            const float* w1p = W1  + (size_t)l * DFF * D;
            const float* b1p = bf1 + (size_t)l * DFF;
            const float* w2p = W2  + (size_t)l * D * DFF;
            for (int f = tid; f < DFF; f += BLK) {
                v4f a;
                a.x = w1p[f * 3 + 0];
                a.y = w1p[f * 3 + 1];
                a.z = w1p[f * 3 + 2];
                a.w = b1p[f];
                s_w1[f] = a;
                s_w2a[f] = (v2f){w2p[f], w2p[DFF + f]};
                s_w2z[f] = w2p[2 * DFF + f];
            }
        }
        __syncthreads();

        // ---- attention: 27 (head,qs) rows split across the 16 lanes ----
        const float* wq = Wqkv + (size_t)l * (3 * D) * D;   // [9][3]
        const float* bq = bqkv + (size_t)l * (3 * D);
        #pragma unroll
        for (int rr = 0; rr < 2; ++rr) {
            const int r = sub + rr * 16;
            if (r < NROW) {
                const int hh = r / 9;
                const int qs = r % 9;
                float q = fmaf(wq[hh * 3 + 0], h[qs][0],
                          fmaf(wq[hh * 3 + 1], h[qs][1],
                          fmaf(wq[hh * 3 + 2], h[qs][2], bq[hh])));
                float kk[S], vv[S];
                #pragma unroll
                for (int s = 0; s < S; ++s) {
                    kk[s] = fmaf(wq[(3 + hh) * 3 + 0], h[s][0],
                            fmaf(wq[(3 + hh) * 3 + 1], h[s][1],
                            fmaf(wq[(3 + hh) * 3 + 2], h[s][2], bq[3 + hh])));
                    vv[s] = fmaf(wq[(6 + hh) * 3 + 0], h[s][0],
                            fmaf(wq[(6 + hh) * 3 + 1], h[s][1],
                            fmaf(wq[(6 + hh) * 3 + 2], h[s][2], bq[6 + hh])));
                }
                float sc[S];
                float m = -1e30f;
                #pragma unroll
                for (int ks = 0; ks < S; ++ks) {
                    sc[ks] = q * kk[ks];
                    m = fmaxf(m, sc[ks]);
                }
                float sum = 0.f, av = 0.f;
                #pragma unroll
                for (int ks = 0; ks < S; ++ks) {
                    float e = __expf(sc[ks] - m);
                    sum += e;
                    av = fmaf(e, vv[ks], av);
                }
                s_att[grp * ATT_STRIDE + r] = av / sum;   // o[qs][hh], r=hh*9+qs
            }
        }
        __syncthreads();

        // ---- Wo projection + residual + LN1 -> h ----
        {
            float o[S][D];
            #pragma unroll
            for (int hh = 0; hh < D; ++hh)
                #pragma unroll
                for (int s = 0; s < S; ++s)
                    o[s][hh] = s_att[grp * ATT_STRIDE + hh * 9 + s];

            const float* wo  = Wo  + (size_t)l * D * D;
            const float* bop = bo  + (size_t)l * D;
            const float* gp  = g1  + (size_t)l * D;
            const float* bp  = be1 + (size_t)l * D;
            #pragma unroll
            for (int s = 0; s < S; ++s) {
                float t[D];
                #pragma unroll
                for (int dd = 0; dd < D; ++dd)
                    t[dd] = h[s][dd] + bop[dd] +
                            fmaf(wo[dd * 3 + 0], o[s][0],
                            fmaf(wo[dd * 3 + 1], o[s][1],
                                 wo[dd * 3 + 2] * o[s][2]));
                float m  = (t[0] + t[1] + t[2]) * (1.f / 3.f);
                float d0 = t[0] - m, d1 = t[1] - m, d2 = t[2] - m;
                float va = (d0 * d0 + d1 * d1 + d2 * d2) * (1.f / 3.f);
                float r  = rsqrtf(va + EPS);
                h[s][0] = fmaf(d0 * r, gp[0], bp[0]);
                h[s][1] = fmaf(d1 * r, gp[1], bp[1]);
                h[s][2] = fmaf(d2 * r, gp[2], bp[2]);
            }
        }

        // ---- FFN, scalar battery: f = i*16 + sub, i in [0,128) ----
        float acc[S][D];
        #pragma unroll
        for (int s = 0; s < S; ++s)
            #pragma unroll
            for (int d = 0; d < D; ++d)
                acc[s][d] = 0.f;

        #pragma unroll 2
        for (int i = 0; i < FPT; ++i) {
            const int f = i * G + sub;
            const v4f  w1  = s_w1[f];
            const v2f  w2a = s_w2a[f];
            const float w2z = s_w2z[f];

            // t[9] battery: 9 independent 3-deep fma chains, kept live together
            float t[S];
            #pragma unroll
            for (int s = 0; s < S; ++s)
                FMA_INIT(t[s], w1.z, h[s][2], w1.w);
            #pragma unroll
            for (int s = 0; s < S; ++s)
                FMA_ACC(t[s], w1.y, h[s][1]);
            #pragma unroll
            for (int s = 0; s < S; ++s)
                FMA_ACC(t[s], w1.x, h[s][0]);
            #pragma unroll
            for (int s = 0; s < S; ++s)
                t[s] = fmaxf(t[s], 0.f);
            #pragma unroll
            for (int s = 0; s < S; ++s) {
                FMA_ACC(acc[s][0], w2a.x, t[s]);
                FMA_ACC(acc[s][1], w2a.y, t[s]);
                FMA_ACC(acc[s][2], w2z,  t[s]);
            }
        }

        // ---- butterfly-reduce the 27 partials across the 16 lanes ----
        #pragma unroll
        for (int mask = 1; mask < G; mask <<= 1) {   // 1,2,4,8
            #pragma unroll
            for (int s = 0; s < S; ++s)
                #pragma unroll
                for (int d = 0; d < D; ++d)
                    acc[s][d] += __shfl_xor(acc[s][d], mask, 64);
        }

        // ---- bf2 + residual + LN2 -> h for next layer ----
        {
            const float* b2p = bf2 + (size_t)l * D;
            const float* gp  = g2  + (size_t)l * D;
            const float* bp  = be2 + (size_t)l * D;
            #pragma unroll
            for (int s = 0; s < S; ++s) {
                float t[D];
                #pragma unroll
                for (int dd = 0; dd < D; ++dd)
                    t[dd] = h[s][dd] + acc[s][dd] + b2p[dd];
                float m  = (t[0] + t[1] + t[2]) * (1.f / 3.f);
                float d0 = t[0] - m, d1 = t[1] - m, d2 = t[2] - m;
                float va = (d0 * d0 + d1 * d1 + d2 * d2) * (1.f / 3.f);
                float r  = rsqrtf(va + EPS);
                h[s][0] = fmaf(d0 * r, gp[0], bp[0]);
                h[s][1] = fmaf(d1 * r, gp[1], bp[1]);
                h[s][2] = fmaf(d2 * r, gp[2], bp[2]);
            }
        }
    }

    // ---- epilogue: z = softmax(h@W) per token, u = prod_s z, softmax(u) ----
    if (sub == 0) {
        float u[S];
        #pragma unroll
        for (int n = 0; n < S; ++n) u[n] = 1.f;
        #pragma unroll
        for (int s = 0; s < S; ++s) {
            float z[S];
            float m = -1e30f;
            #pragma unroll
            for (int n = 0; n < S; ++n) {
                z[n] = fmaf(h[s][0], Wfin[0 * S + n],
                       fmaf(h[s][1], Wfin[1 * S + n],
                            h[s][2] * Wfin[2 * S + n]));
                m = fmaxf(m, z[n]);
            }
            float sum = 0.f;
            #pragma unroll
            for (int n = 0; n < S; ++n) { z[n] = __expf(z[n] - m); sum += z[n]; }
            float inv = 1.f / sum;
            #pragma unroll
            for (int n = 0; n < S; ++n) u[n] *= z[n] * inv;
        }
        float m = -1e30f;
        #pragma unroll
        for (int n = 0; n < S; ++n) m = fmaxf(m, u[n]);
        float e[S];
        float sum = 0.f;
        #pragma unroll
        for (int n = 0; n < S; ++n) { e[n] = __expf(u[n] - m); sum += e[n]; }
        float inv = 1.f / sum;
        float* op = out + (size_t)b * S;
        #pragma unroll
        for (int n = 0; n < S; ++n) op[n] = e[n] * inv;
    }
}

extern "C" void kernel_launch(void* const* d_in, const int* in_sizes, int n_in,
                              void* d_out, int out_size, void* d_ws, size_t ws_size,
                              hipStream_t stream)
{
    const float* x    = (const float*)d_in[0];
    const float* Wqkv = (const float*)d_in[1];
    const float* bqkv = (const float*)d_in[2];
    const float* Wo   = (const float*)d_in[3];
    const float* bo   = (const float*)d_in[4];
    const float* g1   = (const float*)d_in[5];
    const float* be1  = (const float*)d_in[6];
    const float* W1   = (const float*)d_in[7];
    const float* bf1  = (const float*)d_in[8];
    const float* W2   = (const float*)d_in[9];
    const float* bf2  = (const float*)d_in[10];
    const float* g2   = (const float*)d_in[11];
    const float* be2  = (const float*)d_in[12];
    const float* Wfin = (const float*)d_in[13];
    float* out = (float*)d_out;

    const int B = in_sizes[0] / (S * D);       // 8192
    const int nblocks = B / BPB;               // 256 blocks -> 2048 waves

    tf_policy_kernel<<<nblocks, BLK, 0, stream>>>(
        x, Wqkv, bqkv, Wo, bo, g1, be1, W1, bf1, W2, bf2, g2, be2, Wfin, out);
}